// Round 1
// baseline (1189.068 us; speedup 1.0000x reference)
//
#include <hip/hip_runtime.h>
#include <hip/hip_bf16.h>
#include <math.h>

// Problem constants
#define NTOK   8192      // B*S
#define HID    2048
#define DWN    512
#define NEXP   16
#define PADSLOT 17408    // 272*64 >= 16384 + 16*63

// ws layout (bytes)
#define OFF_COMBINED 0                      // float[NTOK*DWN] = 16777216 B
#define OFF_TOK      16777216               // int[PADSLOT]    = 69632 B
#define OFF_PROB     16846848               // float[PADSLOT]  = 69632 B
#define OFF_EIDX     16916480               // int2[NTOK]      = 65536 B
#define OFF_PVAL     16982016               // float2[NTOK]    = 65536 B
#define OFF_COUNTS   17047552               // int[16]
#define OFF_BASE     17047616               // int[17]
#define OFF_CURSOR   17047744               // int[16]
#define OFF_COLSUM   17047808               // float[16]
#define WS_NEEDED    17047872

// ---------------- gating: wave per token, fp64 accumulation ----------------
__global__ __launch_bounds__(256) void gate_kernel(
    const float* __restrict__ x, const float* __restrict__ gw,
    int2* __restrict__ eidx, float2* __restrict__ pvals,
    int* __restrict__ counts, float* __restrict__ colsum)
{
  int lane = threadIdx.x & 63;
  int wave = threadIdx.x >> 6;
  int n = blockIdx.x * 4 + wave;
  const float* xr = x + (size_t)n * HID;
  double acc[NEXP];
#pragma unroll
  for (int e = 0; e < NEXP; e++) acc[e] = 0.0;
  for (int d0 = 0; d0 < HID; d0 += 64) {
    float xv = xr[d0 + lane];
#pragma unroll
    for (int e = 0; e < NEXP; e++)
      acc[e] = fma((double)xv, (double)gw[e * HID + d0 + lane], acc[e]);
  }
#pragma unroll
  for (int e = 0; e < NEXP; e++) {
    double v = acc[e];
#pragma unroll
    for (int off = 32; off > 0; off >>= 1) v += __shfl_xor(v, off, 64);
    acc[e] = v;
  }
  if (lane == 0) {
    double v0 = -1e300, v1 = -1e300;
    int i0 = 0, i1 = 0;
#pragma unroll
    for (int e = 0; e < NEXP; e++) {
      double v = acc[e];
      if (v > v0) { v1 = v0; i1 = i0; v0 = v; i0 = e; }
      else if (v > v1) { v1 = v; i1 = e; }
    }
    double ex = exp(v1 - v0);          // <= 1, stable
    double denom = 1.0 + ex;
    float p0 = (float)(1.0 / denom);
    float p1 = (float)(ex / denom);
    eidx[n] = make_int2(i0, i1);
    pvals[n] = make_float2(p0, p1);
    atomicAdd(&counts[i0], 1);
    atomicAdd(&counts[i1], 1);
    atomicAdd(&colsum[i0], p0);
    atomicAdd(&colsum[i1], p1);
  }
}

// ---------------- scan bases (64-aligned segments) + loss ----------------
__global__ void scan_loss_kernel(const int* __restrict__ counts, int* __restrict__ base,
                                 const float* __restrict__ colsum, float* __restrict__ loss_out)
{
  if (threadIdx.x == 0 && blockIdx.x == 0) {
    int acc = 0;
    for (int e = 0; e < NEXP; e++) { base[e] = acc; acc += (counts[e] + 63) & ~63; }
    base[NEXP] = acc;
    double s = 0.0;
    for (int e = 0; e < NEXP; e++) { double c = (double)colsum[e]; s += c * c; }
    // E * sum(colsum/N * colsum/N) * alpha = 16*0.1*sum(c^2)/N^2
    loss_out[0] = (float)(1.6 * s / ((double)NTOK * (double)NTOK));
  }
}

// ---------------- scatter (counting sort into padded segments) ----------------
__global__ __launch_bounds__(256) void scatter_kernel(
    const int2* __restrict__ eidx, const float2* __restrict__ pvals,
    const int* __restrict__ base, int* __restrict__ cursor,
    int* __restrict__ tok, float* __restrict__ prob)
{
  int n = blockIdx.x * 256 + threadIdx.x;
  int2 e = eidx[n];
  float2 p = pvals[n];
  int pos0 = base[e.x] + atomicAdd(&cursor[e.x], 1);
  tok[pos0] = n; prob[pos0] = p.x;
  int pos1 = base[e.y] + atomicAdd(&cursor[e.y], 1);
  tok[pos1] = n; prob[pos1] = p.y;
}

// ---------------- grouped expert down-proj GEMM (fp32, 64x64 tiles) ----------------
#define LDK 32
#define LSTR 68   // LDS row stride (floats): 272 B, 16B-aligned, breaks pow2 conflicts

__global__ __launch_bounds__(256) void down_gemm_kernel(
    const float* __restrict__ x, const float* __restrict__ dw, const float* __restrict__ db,
    const int* __restrict__ base, const int* __restrict__ tok, const float* __restrict__ prob,
    float* __restrict__ combined)
{
  __shared__ float xs[LDK][LSTR];   // [k][row]  k-major -> b128 fragment reads
  __shared__ float wsd[LDK][LSTR];  // [k][col]
  __shared__ int   tks[64];
  __shared__ float prs[64];

  int slot0 = blockIdx.x * 64;
  int total = base[NEXP];
  if (slot0 >= total) return;            // uniform per block
  int e = 0;
#pragma unroll
  for (int q = 1; q < NEXP; q++) if (base[q] <= slot0) e = q;
  int out0 = blockIdx.y * 64;
  int tid = threadIdx.x;
  if (tid < 64) { tks[tid] = tok[slot0 + tid]; prs[tid] = prob[slot0 + tid]; }
  __syncthreads();

  int lrow = tid >> 2;            // 0..63 (row for x-tile, col for w-tile)
  int lk   = (tid & 3) << 2;      // 0,4,8,12
  int ti   = tid >> 4;            // 0..15 row group
  int tj   = tid & 15;            // 0..15 col group
  int myt  = tks[lrow];
  const float* xrow = (myt >= 0) ? (x + (size_t)myt * HID) : x; // dummy ptr if pad
  const float* wrow = dw + ((size_t)e * DWN + out0 + lrow) * HID;

  float acc[4][4] = {{0.f,0.f,0.f,0.f},{0.f,0.f,0.f,0.f},{0.f,0.f,0.f,0.f},{0.f,0.f,0.f,0.f}};

  for (int k0 = 0; k0 < HID; k0 += LDK) {
    float4 xv0 = make_float4(0.f,0.f,0.f,0.f), xv1 = make_float4(0.f,0.f,0.f,0.f);
    if (myt >= 0) {
      xv0 = *(const float4*)(xrow + k0 + lk);
      xv1 = *(const float4*)(xrow + k0 + lk + 16);
    }
    float4 wv0 = *(const float4*)(wrow + k0 + lk);
    float4 wv1 = *(const float4*)(wrow + k0 + lk + 16);
    __syncthreads();   // previous tile's compute done
    xs[lk+0][lrow] = xv0.x;  xs[lk+1][lrow] = xv0.y;  xs[lk+2][lrow] = xv0.z;  xs[lk+3][lrow] = xv0.w;
    xs[lk+16][lrow] = xv1.x; xs[lk+17][lrow] = xv1.y; xs[lk+18][lrow] = xv1.z; xs[lk+19][lrow] = xv1.w;
    wsd[lk+0][lrow] = wv0.x;  wsd[lk+1][lrow] = wv0.y;  wsd[lk+2][lrow] = wv0.z;  wsd[lk+3][lrow] = wv0.w;
    wsd[lk+16][lrow] = wv1.x; wsd[lk+17][lrow] = wv1.y; wsd[lk+18][lrow] = wv1.z; wsd[lk+19][lrow] = wv1.w;
    __syncthreads();
#pragma unroll
    for (int k = 0; k < LDK; k++) {
      float a0 = xs[k][4*ti+0], a1 = xs[k][4*ti+1], a2 = xs[k][4*ti+2], a3 = xs[k][4*ti+3];
      float b0 = wsd[k][4*tj+0], b1 = wsd[k][4*tj+1], b2 = wsd[k][4*tj+2], b3 = wsd[k][4*tj+3];
      acc[0][0] = fmaf(a0,b0,acc[0][0]); acc[0][1] = fmaf(a0,b1,acc[0][1]);
      acc[0][2] = fmaf(a0,b2,acc[0][2]); acc[0][3] = fmaf(a0,b3,acc[0][3]);
      acc[1][0] = fmaf(a1,b0,acc[1][0]); acc[1][1] = fmaf(a1,b1,acc[1][1]);
      acc[1][2] = fmaf(a1,b2,acc[1][2]); acc[1][3] = fmaf(a1,b3,acc[1][3]);
      acc[2][0] = fmaf(a2,b0,acc[2][0]); acc[2][1] = fmaf(a2,b1,acc[2][1]);
      acc[2][2] = fmaf(a2,b2,acc[2][2]); acc[2][3] = fmaf(a2,b3,acc[2][3]);
      acc[3][0] = fmaf(a3,b0,acc[3][0]); acc[3][1] = fmaf(a3,b1,acc[3][1]);
      acc[3][2] = fmaf(a3,b2,acc[3][2]); acc[3][3] = fmaf(a3,b3,acc[3][3]);
    }
  }

#pragma unroll
  for (int u = 0; u < 4; u++) {
    int r = 4*ti + u;
    int t = tks[r];
    if (t < 0) continue;
    float p = prs[r];
    float* crow = combined + (size_t)t * DWN + out0 + 4*tj;
#pragma unroll
    for (int v = 0; v < 4; v++) {
      float bias = db[e * DWN + out0 + 4*tj + v];
      atomicAdd(&crow[v], p * (acc[u][v] + bias));   // exactly 2 addends/elem: deterministic
    }
  }
}

// ---------------- gelu_new (tanh approx), in place ----------------
__global__ __launch_bounds__(256) void gelu_kernel(float* __restrict__ c)
{
  int idx = blockIdx.x * 256 + threadIdx.x;
  float4 v = ((float4*)c)[idx];
  float* f = (float*)&v;
#pragma unroll
  for (int i = 0; i < 4; i++) {
    float xx = f[i];
    float inner = 0.7978845608028654f * (xx + 0.044715f * xx * xx * xx);
    f[i] = 0.5f * xx * (1.0f + tanhf(inner));
  }
  ((float4*)c)[idx] = v;
}

// ---------------- up-proj GEMM (fp32, 64x64 tiles) ----------------
__global__ __launch_bounds__(256) void up_gemm_kernel(
    const float* __restrict__ h, const float* __restrict__ uw, const float* __restrict__ ub,
    float* __restrict__ out)
{
  __shared__ float hs[LDK][LSTR];
  __shared__ float us[LDK][LSTR];
  int row0 = blockIdx.x * 64;
  int col0 = blockIdx.y * 64;
  int tid = threadIdx.x;
  int lrow = tid >> 2;
  int lk   = (tid & 3) << 2;
  int ti   = tid >> 4;
  int tj   = tid & 15;
  const float* hrow = h  + (size_t)(row0 + lrow) * DWN;
  const float* urow = uw + (size_t)(col0 + lrow) * DWN;

  float acc[4][4] = {{0.f,0.f,0.f,0.f},{0.f,0.f,0.f,0.f},{0.f,0.f,0.f,0.f},{0.f,0.f,0.f,0.f}};

  for (int k0 = 0; k0 < DWN; k0 += LDK) {
    float4 hv0 = *(const float4*)(hrow + k0 + lk);
    float4 hv1 = *(const float4*)(hrow + k0 + lk + 16);
    float4 uv0 = *(const float4*)(urow + k0 + lk);
    float4 uv1 = *(const float4*)(urow + k0 + lk + 16);
    __syncthreads();
    hs[lk+0][lrow] = hv0.x;  hs[lk+1][lrow] = hv0.y;  hs[lk+2][lrow] = hv0.z;  hs[lk+3][lrow] = hv0.w;
    hs[lk+16][lrow] = hv1.x; hs[lk+17][lrow] = hv1.y; hs[lk+18][lrow] = hv1.z; hs[lk+19][lrow] = hv1.w;
    us[lk+0][lrow] = uv0.x;  us[lk+1][lrow] = uv0.y;  us[lk+2][lrow] = uv0.z;  us[lk+3][lrow] = uv0.w;
    us[lk+16][lrow] = uv1.x; us[lk+17][lrow] = uv1.y; us[lk+18][lrow] = uv1.z; us[lk+19][lrow] = uv1.w;
    __syncthreads();
#pragma unroll
    for (int k = 0; k < LDK; k++) {
      float a0 = hs[k][4*ti+0], a1 = hs[k][4*ti+1], a2 = hs[k][4*ti+2], a3 = hs[k][4*ti+3];
      float b0 = us[k][4*tj+0], b1 = us[k][4*tj+1], b2 = us[k][4*tj+2], b3 = us[k][4*tj+3];
      acc[0][0] = fmaf(a0,b0,acc[0][0]); acc[0][1] = fmaf(a0,b1,acc[0][1]);
      acc[0][2] = fmaf(a0,b2,acc[0][2]); acc[0][3] = fmaf(a0,b3,acc[0][3]);
      acc[1][0] = fmaf(a1,b0,acc[1][0]); acc[1][1] = fmaf(a1,b1,acc[1][1]);
      acc[1][2] = fmaf(a1,b2,acc[1][2]); acc[1][3] = fmaf(a1,b3,acc[1][3]);
      acc[2][0] = fmaf(a2,b0,acc[2][0]); acc[2][1] = fmaf(a2,b1,acc[2][1]);
      acc[2][2] = fmaf(a2,b2,acc[2][2]); acc[2][3] = fmaf(a2,b3,acc[2][3]);
      acc[3][0] = fmaf(a3,b0,acc[3][0]); acc[3][1] = fmaf(a3,b1,acc[3][1]);
      acc[3][2] = fmaf(a3,b2,acc[3][2]); acc[3][3] = fmaf(a3,b3,acc[3][3]);
    }
  }

#pragma unroll
  for (int u = 0; u < 4; u++) {
    int r = row0 + 4*ti + u;
    float* orow = out + (size_t)r * HID + col0 + 4*tj;
    float4 o;
    o.x = acc[u][0] + ub[col0 + 4*tj + 0];
    o.y = acc[u][1] + ub[col0 + 4*tj + 1];
    o.z = acc[u][2] + ub[col0 + 4*tj + 2];
    o.w = acc[u][3] + ub[col0 + 4*tj + 3];
    *(float4*)orow = o;
  }
}

extern "C" void kernel_launch(void* const* d_in, const int* in_sizes, int n_in,
                              void* d_out, int out_size, void* d_ws, size_t ws_size,
                              hipStream_t stream)
{
  const float* x  = (const float*)d_in[0];
  const float* gw = (const float*)d_in[1];
  const float* dw = (const float*)d_in[2];
  const float* db = (const float*)d_in[3];
  const float* uw = (const float*)d_in[4];
  const float* ub = (const float*)d_in[5];
  float* out = (float*)d_out;

  char* ws = (char*)d_ws;
  float*  combined = (float*)(ws + OFF_COMBINED);
  int*    tok      = (int*)(ws + OFF_TOK);
  float*  prob     = (float*)(ws + OFF_PROB);
  int2*   eidx     = (int2*)(ws + OFF_EIDX);
  float2* pvals    = (float2*)(ws + OFF_PVAL);
  int*    counts   = (int*)(ws + OFF_COUNTS);
  int*    base     = (int*)(ws + OFF_BASE);
  int*    cursor   = (int*)(ws + OFF_CURSOR);
  float*  colsum   = (float*)(ws + OFF_COLSUM);

  hipMemsetAsync(combined, 0, (size_t)NTOK * DWN * sizeof(float), stream);
  hipMemsetAsync(tok, 0xFF, PADSLOT * sizeof(int), stream);               // token = -1 padding
  hipMemsetAsync(counts, 0, WS_NEEDED - OFF_COUNTS, stream);              // counts/base/cursor/colsum

  gate_kernel<<<NTOK / 4, 256, 0, stream>>>(x, gw, eidx, pvals, counts, colsum);
  scan_loss_kernel<<<1, 64, 0, stream>>>(counts, base, colsum, out + (size_t)NTOK * HID);
  scatter_kernel<<<NTOK / 256, 256, 0, stream>>>(eidx, pvals, base, cursor, tok, prob);

  dim3 gdown(PADSLOT / 64, DWN / 64);       // 272 x 8
  down_gemm_kernel<<<gdown, 256, 0, stream>>>(x, dw, db, base, tok, prob, combined);

  gelu_kernel<<<(NTOK * DWN / 4) / 256, 256, 0, stream>>>(combined);      // 4096 blocks

  dim3 gup(NTOK / 64, HID / 64);            // 128 x 32
  up_gemm_kernel<<<gup, 256, 0, stream>>>(combined, uw, ub, out);
}

// Round 2
// 649.158 us; speedup vs baseline: 1.8317x; 1.8317x over previous
//
#include <hip/hip_runtime.h>
#include <hip/hip_bf16.h>
#include <math.h>

// Problem constants
#define NTOK   8192      // B*S
#define HID    2048
#define DWN    512
#define NEXP   16
#define PADSLOT 18432    // 16384 + 16*128 (segments 128-aligned so a 128-tile never spans experts)

// ws layout (bytes)
#define OFF_COMBINED 0                      // float[NTOK*DWN]      = 16777216
#define OFF_XB       16777216               // bf16[NTOK*HID]       = 33554432
#define OFF_DWB      50331648               // bf16[NEXP*DWN*HID]   = 33554432
#define OFF_UWB      83886080               // bf16[HID*DWN]        = 2097152
#define OFF_H        85983232               // bf16[NTOK*DWN]       = 8388608
#define OFF_TOK      94371840               // int[PADSLOT]         = 73728
#define OFF_PROB     94445568               // float[PADSLOT]       = 73728
#define OFF_EIDX     94519296               // int2[NTOK]           = 65536
#define OFF_PVAL     94584832               // float2[NTOK]         = 65536
#define OFF_COUNTS   94650368               // int[16]
#define OFF_BASE     94650432               // int[17] (padded)
#define OFF_CURSOR   94650560               // int[16]
#define OFF_COLSUM   94650624               // float[16]
#define WS_NEEDED    94650688

typedef __attribute__((ext_vector_type(8))) __bf16 bf16x8;
typedef __attribute__((ext_vector_type(4))) float f32x4;

// async 16B/lane global->LDS copy (LDS dest must be wave-uniform base; HW adds lane*16)
#define ASYNC16(gsrc, ldst) \
  __builtin_amdgcn_global_load_lds((const __attribute__((address_space(1))) unsigned int*)(gsrc), \
                                   (__attribute__((address_space(3))) unsigned int*)(ldst), 16, 0, 0)

__device__ inline unsigned short f2bf(float f) {
  unsigned int u = __float_as_uint(f);
  unsigned int r = (u + 0x7FFFu + ((u >> 16) & 1u)) >> 16;
  return (unsigned short)r;
}

// ---------------- fp32 -> bf16 cast, 8 elems/thread ----------------
__global__ __launch_bounds__(256) void cast8_kernel(const float* __restrict__ src,
                                                    unsigned short* __restrict__ dst)
{
  size_t i = ((size_t)blockIdx.x * 256 + threadIdx.x) * 8;
  float4 a = *(const float4*)(src + i);
  float4 b = *(const float4*)(src + i + 4);
  unsigned short o[8];
  o[0]=f2bf(a.x); o[1]=f2bf(a.y); o[2]=f2bf(a.z); o[3]=f2bf(a.w);
  o[4]=f2bf(b.x); o[5]=f2bf(b.y); o[6]=f2bf(b.z); o[7]=f2bf(b.w);
  *(uint4*)(dst + i) = *(const uint4*)o;
}

// ---------------- gating: wave per token, fp64 accumulation (UNCHANGED from R1: passed) ----------------
__global__ __launch_bounds__(256) void gate_kernel(
    const float* __restrict__ x, const float* __restrict__ gw,
    int2* __restrict__ eidx, float2* __restrict__ pvals,
    int* __restrict__ counts, float* __restrict__ colsum)
{
  int lane = threadIdx.x & 63;
  int wave = threadIdx.x >> 6;
  int n = blockIdx.x * 4 + wave;
  const float* xr = x + (size_t)n * HID;
  double acc[NEXP];
#pragma unroll
  for (int e = 0; e < NEXP; e++) acc[e] = 0.0;
  for (int d0 = 0; d0 < HID; d0 += 64) {
    float xv = xr[d0 + lane];
#pragma unroll
    for (int e = 0; e < NEXP; e++)
      acc[e] = fma((double)xv, (double)gw[e * HID + d0 + lane], acc[e]);
  }
#pragma unroll
  for (int e = 0; e < NEXP; e++) {
    double v = acc[e];
#pragma unroll
    for (int off = 32; off > 0; off >>= 1) v += __shfl_xor(v, off, 64);
    acc[e] = v;
  }
  if (lane == 0) {
    double v0 = -1e300, v1 = -1e300;
    int i0 = 0, i1 = 0;
#pragma unroll
    for (int e = 0; e < NEXP; e++) {
      double v = acc[e];
      if (v > v0) { v1 = v0; i1 = i0; v0 = v; i0 = e; }
      else if (v > v1) { v1 = v; i1 = e; }
    }
    double ex = exp(v1 - v0);
    double denom = 1.0 + ex;
    float p0 = (float)(1.0 / denom);
    float p1 = (float)(ex / denom);
    eidx[n] = make_int2(i0, i1);
    pvals[n] = make_float2(p0, p1);
    atomicAdd(&counts[i0], 1);
    atomicAdd(&counts[i1], 1);
    atomicAdd(&colsum[i0], p0);
    atomicAdd(&colsum[i1], p1);
  }
}

// ---------------- scan bases (128-aligned segments) + loss ----------------
__global__ void scan_loss_kernel(const int* __restrict__ counts, int* __restrict__ base,
                                 const float* __restrict__ colsum, float* __restrict__ loss_out)
{
  if (threadIdx.x == 0 && blockIdx.x == 0) {
    int acc = 0;
    for (int e = 0; e < NEXP; e++) { base[e] = acc; acc += (counts[e] + 127) & ~127; }
    base[NEXP] = acc;
    double s = 0.0;
    for (int e = 0; e < NEXP; e++) { double c = (double)colsum[e]; s += c * c; }
    loss_out[0] = (float)(1.6 * s / ((double)NTOK * (double)NTOK));
  }
}

// ---------------- scatter (counting sort into padded segments) ----------------
__global__ __launch_bounds__(256) void scatter_kernel(
    const int2* __restrict__ eidx, const float2* __restrict__ pvals,
    const int* __restrict__ base, int* __restrict__ cursor,
    int* __restrict__ tok, float* __restrict__ prob)
{
  int n = blockIdx.x * 256 + threadIdx.x;
  int2 e = eidx[n];
  float2 p = pvals[n];
  int pos0 = base[e.x] + atomicAdd(&cursor[e.x], 1);
  tok[pos0] = n; prob[pos0] = p.x;
  int pos1 = base[e.y] + atomicAdd(&cursor[e.y], 1);
  tok[pos1] = n; prob[pos1] = p.y;
}

// ---------------- grouped expert down-proj: bf16 MFMA, 128x128 tile, BK=64 ----------------
// A = xb gathered by slot token (M=PADSLOT), B^T = dwb[e] (N=512 rows, K contig). m97 structure.
__global__ __launch_bounds__(256) void down_mfma_kernel(
    const unsigned short* __restrict__ xb, const unsigned short* __restrict__ dwb,
    const float* __restrict__ db,
    const int* __restrict__ base, const int* __restrict__ tok, const float* __restrict__ prob,
    float* __restrict__ combined)
{
  __shared__ unsigned short As[128 * 64];
  __shared__ unsigned short Bs[128 * 64];
  __shared__ int   tks[128];
  __shared__ float prs[128];

  int slot0 = blockIdx.x * 128;
  if (slot0 >= base[NEXP]) return;          // uniform per block (total is 128-aligned)
  int e = 0;
#pragma unroll
  for (int q = 1; q < NEXP; q++) if (base[q] <= slot0) e = q;
  int out0 = blockIdx.y * 128;

  int tid = threadIdx.x;
  if (tid < 128) { tks[tid] = tok[slot0 + tid]; prs[tid] = prob[slot0 + tid]; }

  const int l = tid & 63, w = tid >> 6;
  const int wm = w & 1, wn = w >> 1;
  const int lm = l & 15, quad = l >> 4;

  // staging: chunk c = (w*4+i)*64 + l; row = c>>3 (128B row), kchunk = c&7 (16B)
  const unsigned short* agp[4];
  const unsigned short* bgp[4];
#pragma unroll
  for (int i = 0; i < 4; i++) {
    int c = (w * 4 + i) * 64 + l;
    int r = c >> 3, kc = c & 7;
    int t = tok[slot0 + r];
    agp[i] = xb + (size_t)(t < 0 ? 0 : t) * HID + kc * 8;
    bgp[i] = dwb + ((size_t)e * DWN + out0 + r) * HID + kc * 8;
  }

  f32x4 acc[4][4] = {};

  for (int k0 = 0; k0 < HID; k0 += 64) {
    __syncthreads();                         // prev iter's LDS reads done
#pragma unroll
    for (int i = 0; i < 4; i++) {
      ASYNC16(agp[i] + k0, &As[(w * 4 + i) * 64 * 8]);
      ASYNC16(bgp[i] + k0, &Bs[(w * 4 + i) * 64 * 8]);
    }
    __syncthreads();                         // drains vmcnt per barrier semantics
#pragma unroll
    for (int kk = 0; kk < 64; kk += 32) {
      bf16x8 af[4], bfr[4];
#pragma unroll
      for (int mi = 0; mi < 4; mi++)
        af[mi] = *(const bf16x8*)&As[(wm * 64 + mi * 16 + lm) * 64 + kk + quad * 8];
#pragma unroll
      for (int ni = 0; ni < 4; ni++)
        bfr[ni] = *(const bf16x8*)&Bs[(wn * 64 + ni * 16 + lm) * 64 + kk + quad * 8];
#pragma unroll
      for (int mi = 0; mi < 4; mi++)
#pragma unroll
        for (int ni = 0; ni < 4; ni++)
          acc[mi][ni] = __builtin_amdgcn_mfma_f32_16x16x32_bf16(af[mi], bfr[ni], acc[mi][ni], 0, 0, 0);
    }
  }

  // epilogue: C/D layout col=lane&15, row=quad*4+reg. Two addends/elem -> atomicAdd.
  float dbv[4];
#pragma unroll
  for (int ni = 0; ni < 4; ni++)
    dbv[ni] = db[e * DWN + out0 + wn * 64 + ni * 16 + lm];
#pragma unroll
  for (int mi = 0; mi < 4; mi++) {
#pragma unroll
    for (int reg = 0; reg < 4; reg++) {
      int m = wm * 64 + mi * 16 + quad * 4 + reg;
      int t = tks[m];
      if (t < 0) continue;
      float p = prs[m];
      float* crow = combined + (size_t)t * DWN;
#pragma unroll
      for (int ni = 0; ni < 4; ni++) {
        int gc = out0 + wn * 64 + ni * 16 + lm;
        atomicAdd(&crow[gc], p * (acc[mi][ni][reg] + dbv[ni]));
      }
    }
  }
}

// ---------------- gelu_new + cast to bf16 ----------------
__global__ __launch_bounds__(256) void gelu_cast_kernel(const float* __restrict__ c,
                                                        unsigned short* __restrict__ h)
{
  size_t i = ((size_t)blockIdx.x * 256 + threadIdx.x) * 8;
  float4 a = *(const float4*)(c + i);
  float4 b = *(const float4*)(c + i + 4);
  float f[8] = {a.x, a.y, a.z, a.w, b.x, b.y, b.z, b.w};
  unsigned short o[8];
#pragma unroll
  for (int j = 0; j < 8; j++) {
    float xx = f[j];
    float inner = 0.7978845608028654f * (xx + 0.044715f * xx * xx * xx);
    o[j] = f2bf(0.5f * xx * (1.0f + tanhf(inner)));
  }
  *(uint4*)(h + i) = *(const uint4*)o;
}

// ---------------- up-proj: bf16 MFMA, 128x128 tile, BK=64, K=512 ----------------
__global__ __launch_bounds__(256) void up_mfma_kernel(
    const unsigned short* __restrict__ h, const unsigned short* __restrict__ uwb,
    const float* __restrict__ ub, float* __restrict__ out)
{
  __shared__ unsigned short As[128 * 64];
  __shared__ unsigned short Bs[128 * 64];

  int row0 = blockIdx.x * 128;
  int col0 = blockIdx.y * 128;
  int tid = threadIdx.x;
  const int l = tid & 63, w = tid >> 6;
  const int wm = w & 1, wn = w >> 1;
  const int lm = l & 15, quad = l >> 4;

  const unsigned short* agp[4];
  const unsigned short* bgp[4];
#pragma unroll
  for (int i = 0; i < 4; i++) {
    int c = (w * 4 + i) * 64 + l;
    int r = c >> 3, kc = c & 7;
    agp[i] = h   + (size_t)(row0 + r) * DWN + kc * 8;
    bgp[i] = uwb + (size_t)(col0 + r) * DWN + kc * 8;
  }

  f32x4 acc[4][4] = {};

  for (int k0 = 0; k0 < DWN; k0 += 64) {
    __syncthreads();
#pragma unroll
    for (int i = 0; i < 4; i++) {
      ASYNC16(agp[i] + k0, &As[(w * 4 + i) * 64 * 8]);
      ASYNC16(bgp[i] + k0, &Bs[(w * 4 + i) * 64 * 8]);
    }
    __syncthreads();
#pragma unroll
    for (int kk = 0; kk < 64; kk += 32) {
      bf16x8 af[4], bfr[4];
#pragma unroll
      for (int mi = 0; mi < 4; mi++)
        af[mi] = *(const bf16x8*)&As[(wm * 64 + mi * 16 + lm) * 64 + kk + quad * 8];
#pragma unroll
      for (int ni = 0; ni < 4; ni++)
        bfr[ni] = *(const bf16x8*)&Bs[(wn * 64 + ni * 16 + lm) * 64 + kk + quad * 8];
#pragma unroll
      for (int mi = 0; mi < 4; mi++)
#pragma unroll
        for (int ni = 0; ni < 4; ni++)
          acc[mi][ni] = __builtin_amdgcn_mfma_f32_16x16x32_bf16(af[mi], bfr[ni], acc[mi][ni], 0, 0, 0);
    }
  }

  float ubv[4];
#pragma unroll
  for (int ni = 0; ni < 4; ni++)
    ubv[ni] = ub[col0 + wn * 64 + ni * 16 + lm];
#pragma unroll
  for (int mi = 0; mi < 4; mi++) {
#pragma unroll
    for (int reg = 0; reg < 4; reg++) {
      int m = row0 + wm * 64 + mi * 16 + quad * 4 + reg;
      float* orow = out + (size_t)m * HID;
#pragma unroll
      for (int ni = 0; ni < 4; ni++) {
        int gc = col0 + wn * 64 + ni * 16 + lm;
        orow[gc] = acc[mi][ni][reg] + ubv[ni];
      }
    }
  }
}

extern "C" void kernel_launch(void* const* d_in, const int* in_sizes, int n_in,
                              void* d_out, int out_size, void* d_ws, size_t ws_size,
                              hipStream_t stream)
{
  const float* x  = (const float*)d_in[0];
  const float* gw = (const float*)d_in[1];
  const float* dw = (const float*)d_in[2];
  const float* db = (const float*)d_in[3];
  const float* uw = (const float*)d_in[4];
  const float* ub = (const float*)d_in[5];
  float* out = (float*)d_out;

  char* ws = (char*)d_ws;
  float*          combined = (float*)(ws + OFF_COMBINED);
  unsigned short* xb       = (unsigned short*)(ws + OFF_XB);
  unsigned short* dwb      = (unsigned short*)(ws + OFF_DWB);
  unsigned short* uwb      = (unsigned short*)(ws + OFF_UWB);
  unsigned short* h        = (unsigned short*)(ws + OFF_H);
  int*    tok    = (int*)(ws + OFF_TOK);
  float*  prob   = (float*)(ws + OFF_PROB);
  int2*   eidx   = (int2*)(ws + OFF_EIDX);
  float2* pvals  = (float2*)(ws + OFF_PVAL);
  int*    counts = (int*)(ws + OFF_COUNTS);
  int*    base   = (int*)(ws + OFF_BASE);
  int*    cursor = (int*)(ws + OFF_CURSOR);
  float*  colsum = (float*)(ws + OFF_COLSUM);

  hipMemsetAsync(combined, 0, (size_t)NTOK * DWN * sizeof(float), stream);
  hipMemsetAsync(tok, 0xFF, PADSLOT * sizeof(int), stream);     // token = -1 padding
  hipMemsetAsync(counts, 0, WS_NEEDED - OFF_COUNTS, stream);    // counts/base/cursor/colsum

  // casts (independent of gating)
  cast8_kernel<<<(NTOK * HID) / 8 / 256, 256, 0, stream>>>(x, xb);           // 8192 blocks
  cast8_kernel<<<(NEXP * DWN * HID) / 8 / 256, 256, 0, stream>>>(dw, dwb);   // 8192 blocks
  cast8_kernel<<<(HID * DWN) / 8 / 256, 256, 0, stream>>>(uw, uwb);          // 512 blocks

  gate_kernel<<<NTOK / 4, 256, 0, stream>>>(x, gw, eidx, pvals, counts, colsum);
  scan_loss_kernel<<<1, 64, 0, stream>>>(counts, base, colsum, out + (size_t)NTOK * HID);
  scatter_kernel<<<NTOK / 256, 256, 0, stream>>>(eidx, pvals, base, cursor, tok, prob);

  dim3 gdown(PADSLOT / 128, DWN / 128);     // 144 x 4
  down_mfma_kernel<<<gdown, 256, 0, stream>>>(xb, dwb, db, base, tok, prob, combined);

  gelu_cast_kernel<<<(NTOK * DWN) / 8 / 256, 256, 0, stream>>>(combined, h); // 2048 blocks

  dim3 gup(NTOK / 128, HID / 128);          // 64 x 16
  up_mfma_kernel<<<gup, 256, 0, stream>>>(h, uwb, ub, out);
}

// Round 3
// 434.376 us; speedup vs baseline: 2.7374x; 1.4945x over previous
//
#include <hip/hip_runtime.h>
#include <hip/hip_bf16.h>
#include <math.h>

// Problem constants
#define NTOK   8192      // B*S
#define HID    2048
#define DWN    512
#define NEXP   16
#define PADSLOT 18432    // 16384 + 16*128 (segments 128-aligned so a 128-tile never spans experts)

// ws layout (bytes)
#define OFF_COMBINED 0                      // float[NTOK*DWN]      = 16777216
#define OFF_XB       16777216               // bf16[NTOK*HID]       = 33554432
#define OFF_DWB      50331648               // bf16[NEXP*DWN*HID]   = 33554432
#define OFF_UWB      83886080               // bf16[HID*DWN]        = 2097152
#define OFF_H        85983232               // bf16[NTOK*DWN]       = 8388608
#define OFF_TOK      94371840               // int[PADSLOT]         = 73728
#define OFF_PROB     94445568               // float[PADSLOT]       = 73728
#define OFF_EIDX     94519296               // int2[NTOK]           = 65536
#define OFF_PVAL     94584832               // float2[NTOK]         = 65536
#define OFF_COUNTS   94650368               // int[16]
#define OFF_BASE     94650432               // int[17] (padded)
#define OFF_CURSOR   94650560               // int[16]
#define OFF_COLSUM   94650624               // float[16]
#define WS_NEEDED    94650688

typedef __attribute__((ext_vector_type(8))) __bf16 bf16x8;
typedef __attribute__((ext_vector_type(4))) float f32x4;

// async 16B/lane global->LDS copy (LDS dest must be wave-uniform base; HW adds lane*16)
#define ASYNC16(gsrc, ldst) \
  __builtin_amdgcn_global_load_lds((const __attribute__((address_space(1))) unsigned int*)(gsrc), \
                                   (__attribute__((address_space(3))) unsigned int*)(ldst), 16, 0, 0)

__device__ inline unsigned short f2bf(float f) {
  unsigned int u = __float_as_uint(f);
  unsigned int r = (u + 0x7FFFu + ((u >> 16) & 1u)) >> 16;
  return (unsigned short)r;
}

// ---------------- fp32 -> bf16 cast, 8 elems/thread ----------------
__global__ __launch_bounds__(256) void cast8_kernel(const float* __restrict__ src,
                                                    unsigned short* __restrict__ dst)
{
  size_t i = ((size_t)blockIdx.x * 256 + threadIdx.x) * 8;
  float4 a = *(const float4*)(src + i);
  float4 b = *(const float4*)(src + i + 4);
  unsigned short o[8];
  o[0]=f2bf(a.x); o[1]=f2bf(a.y); o[2]=f2bf(a.z); o[3]=f2bf(a.w);
  o[4]=f2bf(b.x); o[5]=f2bf(b.y); o[6]=f2bf(b.z); o[7]=f2bf(b.w);
  *(uint4*)(dst + i) = *(const uint4*)o;
}

// ---------------- gating: wave per token, fp64, NAMED accumulators (no scratch array),
// NO global atomics. Arithmetic order bit-identical to the R1/R2 gate that passed. ----------------
__global__ __launch_bounds__(256) void gate_kernel(
    const float* __restrict__ x, const float* __restrict__ gw,
    int2* __restrict__ eidx, float2* __restrict__ pvals)
{
  int lane = threadIdx.x & 63;
  int wave = threadIdx.x >> 6;
  int n = blockIdx.x * 4 + wave;
  const float* xr  = x + (size_t)n * HID;
  const float* gwp = gw + lane;

  double a0=0,a1=0,a2=0,a3=0,a4=0,a5=0,a6=0,a7=0;
  double a8=0,a9=0,a10=0,a11=0,a12=0,a13=0,a14=0,a15=0;

  for (int d0 = 0; d0 < HID; d0 += 64) {
    double xd = (double)xr[d0 + lane];
    const float* g = gwp + d0;
    a0  = fma(xd, (double)g[ 0*HID], a0);
    a1  = fma(xd, (double)g[ 1*HID], a1);
    a2  = fma(xd, (double)g[ 2*HID], a2);
    a3  = fma(xd, (double)g[ 3*HID], a3);
    a4  = fma(xd, (double)g[ 4*HID], a4);
    a5  = fma(xd, (double)g[ 5*HID], a5);
    a6  = fma(xd, (double)g[ 6*HID], a6);
    a7  = fma(xd, (double)g[ 7*HID], a7);
    a8  = fma(xd, (double)g[ 8*HID], a8);
    a9  = fma(xd, (double)g[ 9*HID], a9);
    a10 = fma(xd, (double)g[10*HID], a10);
    a11 = fma(xd, (double)g[11*HID], a11);
    a12 = fma(xd, (double)g[12*HID], a12);
    a13 = fma(xd, (double)g[13*HID], a13);
    a14 = fma(xd, (double)g[14*HID], a14);
    a15 = fma(xd, (double)g[15*HID], a15);
  }

  // butterfly reduce, same offset order as R1 (32,16,8,4,2,1)
#define RED(v) { v += __shfl_xor(v,32,64); v += __shfl_xor(v,16,64); v += __shfl_xor(v,8,64); \
                 v += __shfl_xor(v,4,64);  v += __shfl_xor(v,2,64);  v += __shfl_xor(v,1,64); }
  RED(a0) RED(a1) RED(a2) RED(a3) RED(a4) RED(a5) RED(a6) RED(a7)
  RED(a8) RED(a9) RED(a10) RED(a11) RED(a12) RED(a13) RED(a14) RED(a15)
#undef RED

  if (lane == 0) {
    double v0 = -1e300, v1 = -1e300;
    int i0 = 0, i1 = 0;
#define TOP(v,E) { if ((v) > v0) { v1 = v0; i1 = i0; v0 = (v); i0 = (E); } \
                   else if ((v) > v1) { v1 = (v); i1 = (E); } }
    TOP(a0,0) TOP(a1,1) TOP(a2,2) TOP(a3,3) TOP(a4,4) TOP(a5,5) TOP(a6,6) TOP(a7,7)
    TOP(a8,8) TOP(a9,9) TOP(a10,10) TOP(a11,11) TOP(a12,12) TOP(a13,13) TOP(a14,14) TOP(a15,15)
#undef TOP
    double ex = exp(v1 - v0);
    double denom = 1.0 + ex;
    eidx[n]  = make_int2(i0, i1);
    pvals[n] = make_float2((float)(1.0 / denom), (float)(ex / denom));
  }
}

// ---------------- histogram: counts + colsum via LDS bins (512 global atomics total) ----------------
__global__ __launch_bounds__(256) void hist_kernel(
    const int2* __restrict__ eidx, const float2* __restrict__ pvals,
    int* __restrict__ counts, float* __restrict__ colsum)
{
  __shared__ int   cbin[NEXP];
  __shared__ float lbin[NEXP];
  if (threadIdx.x < NEXP) { cbin[threadIdx.x] = 0; lbin[threadIdx.x] = 0.f; }
  __syncthreads();
  int n = blockIdx.x * 256 + threadIdx.x;
  int2 e = eidx[n];
  float2 p = pvals[n];
  atomicAdd(&cbin[e.x], 1);  atomicAdd(&lbin[e.x], p.x);
  atomicAdd(&cbin[e.y], 1);  atomicAdd(&lbin[e.y], p.y);
  __syncthreads();
  if (threadIdx.x < NEXP) {
    atomicAdd(&counts[threadIdx.x], cbin[threadIdx.x]);
    atomicAdd(&colsum[threadIdx.x], lbin[threadIdx.x]);
  }
}

// ---------------- scan bases (128-aligned segments) + loss ----------------
__global__ void scan_loss_kernel(const int* __restrict__ counts, int* __restrict__ base,
                                 const float* __restrict__ colsum, float* __restrict__ loss_out)
{
  if (threadIdx.x == 0 && blockIdx.x == 0) {
    int acc = 0;
    for (int e = 0; e < NEXP; e++) { base[e] = acc; acc += (counts[e] + 127) & ~127; }
    base[NEXP] = acc;
    double s = 0.0;
    for (int e = 0; e < NEXP; e++) { double c = (double)colsum[e]; s += c * c; }
    loss_out[0] = (float)(1.6 * s / ((double)NTOK * (double)NTOK));
  }
}

// ---------------- scatter: wave-aggregated cursor atomics ----------------
__global__ __launch_bounds__(256) void scatter_kernel(
    const int2* __restrict__ eidx, const float2* __restrict__ pvals,
    const int* __restrict__ base, int* __restrict__ cursor,
    int* __restrict__ tok, float* __restrict__ prob)
{
  int n = blockIdx.x * 256 + threadIdx.x;
  int lane = threadIdx.x & 63;
  int2 e = eidx[n];
  float2 p = pvals[n];
  int   myE[2] = {e.x, e.y};
  float myP[2] = {p.x, p.y};
#pragma unroll
  for (int s = 0; s < 2; s++) {
    int eq = myE[s];
#pragma unroll
    for (int q = 0; q < NEXP; q++) {
      unsigned long long m = __ballot(eq == q);
      if (eq == q) {
        int cnt = __popcll(m);
        int pre = __popcll(m & ((1ull << lane) - 1ull));
        int b = 0;
        if (pre == 0) b = atomicAdd(&cursor[q], cnt);
        int leader = __ffsll((long long)m) - 1;
        b = __shfl(b, leader, 64);
        int pos = base[q] + b + pre;
        tok[pos] = n; prob[pos] = myP[s];
      }
    }
  }
}

// ---------------- grouped expert down-proj: bf16 MFMA, 128x128 tile, BK=64 ----------------
__global__ __launch_bounds__(256) void down_mfma_kernel(
    const unsigned short* __restrict__ xb, const unsigned short* __restrict__ dwb,
    const float* __restrict__ db,
    const int* __restrict__ base, const int* __restrict__ tok, const float* __restrict__ prob,
    float* __restrict__ combined)
{
  __shared__ unsigned short As[128 * 64];
  __shared__ unsigned short Bs[128 * 64];
  __shared__ int   tks[128];
  __shared__ float prs[128];

  int slot0 = blockIdx.x * 128;
  if (slot0 >= base[NEXP]) return;          // uniform per block (total is 128-aligned)
  int e = 0;
#pragma unroll
  for (int q = 1; q < NEXP; q++) if (base[q] <= slot0) e = q;
  int out0 = blockIdx.y * 128;

  int tid = threadIdx.x;
  if (tid < 128) { tks[tid] = tok[slot0 + tid]; prs[tid] = prob[slot0 + tid]; }

  const int l = tid & 63, w = tid >> 6;
  const int wm = w & 1, wn = w >> 1;
  const int lm = l & 15, quad = l >> 4;

  const unsigned short* agp[4];
  const unsigned short* bgp[4];
#pragma unroll
  for (int i = 0; i < 4; i++) {
    int c = (w * 4 + i) * 64 + l;
    int r = c >> 3, kc = c & 7;
    int t = tok[slot0 + r];
    agp[i] = xb + (size_t)(t < 0 ? 0 : t) * HID + kc * 8;
    bgp[i] = dwb + ((size_t)e * DWN + out0 + r) * HID + kc * 8;
  }

  f32x4 acc[4][4] = {};

  for (int k0 = 0; k0 < HID; k0 += 64) {
    __syncthreads();
#pragma unroll
    for (int i = 0; i < 4; i++) {
      ASYNC16(agp[i] + k0, &As[(w * 4 + i) * 64 * 8]);
      ASYNC16(bgp[i] + k0, &Bs[(w * 4 + i) * 64 * 8]);
    }
    __syncthreads();
#pragma unroll
    for (int kk = 0; kk < 64; kk += 32) {
      bf16x8 af[4], bfr[4];
#pragma unroll
      for (int mi = 0; mi < 4; mi++)
        af[mi] = *(const bf16x8*)&As[(wm * 64 + mi * 16 + lm) * 64 + kk + quad * 8];
#pragma unroll
      for (int ni = 0; ni < 4; ni++)
        bfr[ni] = *(const bf16x8*)&Bs[(wn * 64 + ni * 16 + lm) * 64 + kk + quad * 8];
#pragma unroll
      for (int mi = 0; mi < 4; mi++)
#pragma unroll
        for (int ni = 0; ni < 4; ni++)
          acc[mi][ni] = __builtin_amdgcn_mfma_f32_16x16x32_bf16(af[mi], bfr[ni], acc[mi][ni], 0, 0, 0);
    }
  }

  float dbv[4];
#pragma unroll
  for (int ni = 0; ni < 4; ni++)
    dbv[ni] = db[e * DWN + out0 + wn * 64 + ni * 16 + lm];
#pragma unroll
  for (int mi = 0; mi < 4; mi++) {
#pragma unroll
    for (int reg = 0; reg < 4; reg++) {
      int m = wm * 64 + mi * 16 + quad * 4 + reg;
      int t = tks[m];
      if (t < 0) continue;
      float p = prs[m];
      float* crow = combined + (size_t)t * DWN;
#pragma unroll
      for (int ni = 0; ni < 4; ni++) {
        int gc = out0 + wn * 64 + ni * 16 + lm;
        atomicAdd(&crow[gc], p * (acc[mi][ni][reg] + dbv[ni]));
      }
    }
  }
}

// ---------------- gelu_new + cast to bf16 ----------------
__global__ __launch_bounds__(256) void gelu_cast_kernel(const float* __restrict__ c,
                                                        unsigned short* __restrict__ h)
{
  size_t i = ((size_t)blockIdx.x * 256 + threadIdx.x) * 8;
  float4 a = *(const float4*)(c + i);
  float4 b = *(const float4*)(c + i + 4);
  float f[8] = {a.x, a.y, a.z, a.w, b.x, b.y, b.z, b.w};
  unsigned short o[8];
#pragma unroll
  for (int j = 0; j < 8; j++) {
    float xx = f[j];
    float inner = 0.7978845608028654f * (xx + 0.044715f * xx * xx * xx);
    o[j] = f2bf(0.5f * xx * (1.0f + tanhf(inner)));
  }
  *(uint4*)(h + i) = *(const uint4*)o;
}

// ---------------- up-proj: bf16 MFMA, 128x128 tile, BK=64, K=512 ----------------
__global__ __launch_bounds__(256) void up_mfma_kernel(
    const unsigned short* __restrict__ h, const unsigned short* __restrict__ uwb,
    const float* __restrict__ ub, float* __restrict__ out)
{
  __shared__ unsigned short As[128 * 64];
  __shared__ unsigned short Bs[128 * 64];

  int row0 = blockIdx.x * 128;
  int col0 = blockIdx.y * 128;
  int tid = threadIdx.x;
  const int l = tid & 63, w = tid >> 6;
  const int wm = w & 1, wn = w >> 1;
  const int lm = l & 15, quad = l >> 4;

  const unsigned short* agp[4];
  const unsigned short* bgp[4];
#pragma unroll
  for (int i = 0; i < 4; i++) {
    int c = (w * 4 + i) * 64 + l;
    int r = c >> 3, kc = c & 7;
    agp[i] = h   + (size_t)(row0 + r) * DWN + kc * 8;
    bgp[i] = uwb + (size_t)(col0 + r) * DWN + kc * 8;
  }

  f32x4 acc[4][4] = {};

  for (int k0 = 0; k0 < DWN; k0 += 64) {
    __syncthreads();
#pragma unroll
    for (int i = 0; i < 4; i++) {
      ASYNC16(agp[i] + k0, &As[(w * 4 + i) * 64 * 8]);
      ASYNC16(bgp[i] + k0, &Bs[(w * 4 + i) * 64 * 8]);
    }
    __syncthreads();
#pragma unroll
    for (int kk = 0; kk < 64; kk += 32) {
      bf16x8 af[4], bfr[4];
#pragma unroll
      for (int mi = 0; mi < 4; mi++)
        af[mi] = *(const bf16x8*)&As[(wm * 64 + mi * 16 + lm) * 64 + kk + quad * 8];
#pragma unroll
      for (int ni = 0; ni < 4; ni++)
        bfr[ni] = *(const bf16x8*)&Bs[(wn * 64 + ni * 16 + lm) * 64 + kk + quad * 8];
#pragma unroll
      for (int mi = 0; mi < 4; mi++)
#pragma unroll
        for (int ni = 0; ni < 4; ni++)
          acc[mi][ni] = __builtin_amdgcn_mfma_f32_16x16x32_bf16(af[mi], bfr[ni], acc[mi][ni], 0, 0, 0);
    }
  }

  float ubv[4];
#pragma unroll
  for (int ni = 0; ni < 4; ni++)
    ubv[ni] = ub[col0 + wn * 64 + ni * 16 + lm];
#pragma unroll
  for (int mi = 0; mi < 4; mi++) {
#pragma unroll
    for (int reg = 0; reg < 4; reg++) {
      int m = row0 + wm * 64 + mi * 16 + quad * 4 + reg;
      float* orow = out + (size_t)m * HID;
#pragma unroll
      for (int ni = 0; ni < 4; ni++) {
        int gc = col0 + wn * 64 + ni * 16 + lm;
        orow[gc] = acc[mi][ni][reg] + ubv[ni];
      }
    }
  }
}

extern "C" void kernel_launch(void* const* d_in, const int* in_sizes, int n_in,
                              void* d_out, int out_size, void* d_ws, size_t ws_size,
                              hipStream_t stream)
{
  const float* x  = (const float*)d_in[0];
  const float* gw = (const float*)d_in[1];
  const float* dw = (const float*)d_in[2];
  const float* db = (const float*)d_in[3];
  const float* uw = (const float*)d_in[4];
  const float* ub = (const float*)d_in[5];
  float* out = (float*)d_out;

  char* ws = (char*)d_ws;
  float*          combined = (float*)(ws + OFF_COMBINED);
  unsigned short* xb       = (unsigned short*)(ws + OFF_XB);
  unsigned short* dwb      = (unsigned short*)(ws + OFF_DWB);
  unsigned short* uwb      = (unsigned short*)(ws + OFF_UWB);
  unsigned short* h        = (unsigned short*)(ws + OFF_H);
  int*    tok    = (int*)(ws + OFF_TOK);
  float*  prob   = (float*)(ws + OFF_PROB);
  int2*   eidx   = (int2*)(ws + OFF_EIDX);
  float2* pvals  = (float2*)(ws + OFF_PVAL);
  int*    counts = (int*)(ws + OFF_COUNTS);
  int*    base   = (int*)(ws + OFF_BASE);
  int*    cursor = (int*)(ws + OFF_CURSOR);
  float*  colsum = (float*)(ws + OFF_COLSUM);

  hipMemsetAsync(combined, 0, (size_t)NTOK * DWN * sizeof(float), stream);
  hipMemsetAsync(tok, 0xFF, PADSLOT * sizeof(int), stream);     // token = -1 padding
  hipMemsetAsync(counts, 0, WS_NEEDED - OFF_COUNTS, stream);    // counts/base/cursor/colsum

  // casts (independent of gating)
  cast8_kernel<<<(NTOK * HID) / 8 / 256, 256, 0, stream>>>(x, xb);           // 8192 blocks
  cast8_kernel<<<(NEXP * DWN * HID) / 8 / 256, 256, 0, stream>>>(dw, dwb);   // 8192 blocks
  cast8_kernel<<<(HID * DWN) / 8 / 256, 256, 0, stream>>>(uw, uwb);          // 512 blocks

  gate_kernel<<<NTOK / 4, 256, 0, stream>>>(x, gw, eidx, pvals);
  hist_kernel<<<NTOK / 256, 256, 0, stream>>>(eidx, pvals, counts, colsum);
  scan_loss_kernel<<<1, 64, 0, stream>>>(counts, base, colsum, out + (size_t)NTOK * HID);
  scatter_kernel<<<NTOK / 256, 256, 0, stream>>>(eidx, pvals, base, cursor, tok, prob);

  dim3 gdown(PADSLOT / 128, DWN / 128);     // 144 x 4
  down_mfma_kernel<<<gdown, 256, 0, stream>>>(xb, dwb, db, base, tok, prob, combined);

  gelu_cast_kernel<<<(NTOK * DWN) / 8 / 256, 256, 0, stream>>>(combined, h); // 2048 blocks

  dim3 gup(NTOK / 128, HID / 128);          // 64 x 16
  up_mfma_kernel<<<gup, 256, 0, stream>>>(h, uwb, ub, out);
}

// Round 4
// 426.638 us; speedup vs baseline: 2.7871x; 1.0181x over previous
//
#include <hip/hip_runtime.h>
#include <hip/hip_bf16.h>
#include <math.h>

// Problem constants
#define NTOK   8192      // B*S
#define HID    2048
#define DWN    512
#define NEXP   16
#define PADSLOT 18432    // 144*128 >= 16384 + 16*127 (segments 128-aligned)

// ws layout (bytes). H overlays DWB (dwb dead after down_mfma; combine writes h after).
#define OFF_XB       0                       // bf16[NTOK*HID]       = 33554432
#define OFF_DWB      33554432                // bf16[NEXP*DWN*HID]   = 33554432
#define OFF_H        33554432                // bf16[NTOK*DWN]       = 8388608 (overlay on DWB)
#define OFF_UWB      67108864                // bf16[HID*DWN]        = 2097152
#define OFF_TOK      69206016                // int[PADSLOT]         = 73728
#define OFF_SPOS     69279744                // int2[NTOK]           = 65536
#define OFF_EIDX     69345280                // int2[NTOK]           = 65536
#define OFF_PVAL     69410816                // float2[NTOK]         = 65536
#define OFF_COUNTS   69476352                // int[16]
#define OFF_BASE     69476416                // int[17] (padded to 128)
#define OFF_CURSOR   69476544                // int[16]
#define OFF_COLSUM   69476608                // float[16]
#define OFF_SEG      69476672                // bf16[ksplit][PADSLOT*512]
#define SEGHALF_SHORTS 9437184               // PADSLOT*512
#define SEGHALF_BYTES  18874368
#define WS_NEED1     (OFF_SEG + 1 * SEGHALF_BYTES)   //  88.4 MB (known-safe: R3 used 94.65 MB)
#define WS_NEED2     (OFF_SEG + 2 * SEGHALF_BYTES)   // 107.2 MB

typedef __attribute__((ext_vector_type(8))) __bf16 bf16x8;
typedef __attribute__((ext_vector_type(4))) float f32x4;

// async 16B/lane global->LDS copy (LDS dest is wave-uniform base; HW adds lane*16)
#define ASYNC16(gsrc, ldst) \
  __builtin_amdgcn_global_load_lds((const __attribute__((address_space(1))) unsigned int*)(gsrc), \
                                   (__attribute__((address_space(3))) unsigned int*)(ldst), 16, 0, 0)

__device__ inline unsigned short f2bf(float f) {
  unsigned int u = __float_as_uint(f);
  unsigned int r = (u + 0x7FFFu + ((u >> 16) & 1u)) >> 16;
  return (unsigned short)r;
}
__device__ inline float bf2f(unsigned short s) {
  return __uint_as_float((unsigned int)s << 16);
}

// ---------------- fp32 -> bf16 cast, 8 elems/thread ----------------
__global__ __launch_bounds__(256) void cast8_kernel(const float* __restrict__ src,
                                                    unsigned short* __restrict__ dst)
{
  size_t i = ((size_t)blockIdx.x * 256 + threadIdx.x) * 8;
  float4 a = *(const float4*)(src + i);
  float4 b = *(const float4*)(src + i + 4);
  unsigned short o[8];
  o[0]=f2bf(a.x); o[1]=f2bf(a.y); o[2]=f2bf(a.z); o[3]=f2bf(a.w);
  o[4]=f2bf(b.x); o[5]=f2bf(b.y); o[6]=f2bf(b.z); o[7]=f2bf(b.w);
  *(uint4*)(dst + i) = *(const uint4*)o;
}

// ---------------- gating: FROZEN from R3 (bit-identical selection, passed twice) ----------------
__global__ __launch_bounds__(256) void gate_kernel(
    const float* __restrict__ x, const float* __restrict__ gw,
    int2* __restrict__ eidx, float2* __restrict__ pvals)
{
  int lane = threadIdx.x & 63;
  int wave = threadIdx.x >> 6;
  int n = blockIdx.x * 4 + wave;
  const float* xr  = x + (size_t)n * HID;
  const float* gwp = gw + lane;

  double a0=0,a1=0,a2=0,a3=0,a4=0,a5=0,a6=0,a7=0;
  double a8=0,a9=0,a10=0,a11=0,a12=0,a13=0,a14=0,a15=0;

  for (int d0 = 0; d0 < HID; d0 += 64) {
    double xd = (double)xr[d0 + lane];
    const float* g = gwp + d0;
    a0  = fma(xd, (double)g[ 0*HID], a0);
    a1  = fma(xd, (double)g[ 1*HID], a1);
    a2  = fma(xd, (double)g[ 2*HID], a2);
    a3  = fma(xd, (double)g[ 3*HID], a3);
    a4  = fma(xd, (double)g[ 4*HID], a4);
    a5  = fma(xd, (double)g[ 5*HID], a5);
    a6  = fma(xd, (double)g[ 6*HID], a6);
    a7  = fma(xd, (double)g[ 7*HID], a7);
    a8  = fma(xd, (double)g[ 8*HID], a8);
    a9  = fma(xd, (double)g[ 9*HID], a9);
    a10 = fma(xd, (double)g[10*HID], a10);
    a11 = fma(xd, (double)g[11*HID], a11);
    a12 = fma(xd, (double)g[12*HID], a12);
    a13 = fma(xd, (double)g[13*HID], a13);
    a14 = fma(xd, (double)g[14*HID], a14);
    a15 = fma(xd, (double)g[15*HID], a15);
  }

#define RED(v) { v += __shfl_xor(v,32,64); v += __shfl_xor(v,16,64); v += __shfl_xor(v,8,64); \
                 v += __shfl_xor(v,4,64);  v += __shfl_xor(v,2,64);  v += __shfl_xor(v,1,64); }
  RED(a0) RED(a1) RED(a2) RED(a3) RED(a4) RED(a5) RED(a6) RED(a7)
  RED(a8) RED(a9) RED(a10) RED(a11) RED(a12) RED(a13) RED(a14) RED(a15)
#undef RED

  if (lane == 0) {
    double v0 = -1e300, v1 = -1e300;
    int i0 = 0, i1 = 0;
#define TOP(v,E) { if ((v) > v0) { v1 = v0; i1 = i0; v0 = (v); i0 = (E); } \
                   else if ((v) > v1) { v1 = (v); i1 = (E); } }
    TOP(a0,0) TOP(a1,1) TOP(a2,2) TOP(a3,3) TOP(a4,4) TOP(a5,5) TOP(a6,6) TOP(a7,7)
    TOP(a8,8) TOP(a9,9) TOP(a10,10) TOP(a11,11) TOP(a12,12) TOP(a13,13) TOP(a14,14) TOP(a15,15)
#undef TOP
    double ex = exp(v1 - v0);
    double denom = 1.0 + ex;
    eidx[n]  = make_int2(i0, i1);
    pvals[n] = make_float2((float)(1.0 / denom), (float)(ex / denom));
  }
}

// ---------------- histogram: counts + colsum via LDS bins ----------------
__global__ __launch_bounds__(256) void hist_kernel(
    const int2* __restrict__ eidx, const float2* __restrict__ pvals,
    int* __restrict__ counts, float* __restrict__ colsum)
{
  __shared__ int   cbin[NEXP];
  __shared__ float lbin[NEXP];
  if (threadIdx.x < NEXP) { cbin[threadIdx.x] = 0; lbin[threadIdx.x] = 0.f; }
  __syncthreads();
  int n = blockIdx.x * 256 + threadIdx.x;
  int2 e = eidx[n];
  float2 p = pvals[n];
  atomicAdd(&cbin[e.x], 1);  atomicAdd(&lbin[e.x], p.x);
  atomicAdd(&cbin[e.y], 1);  atomicAdd(&lbin[e.y], p.y);
  __syncthreads();
  if (threadIdx.x < NEXP) {
    atomicAdd(&counts[threadIdx.x], cbin[threadIdx.x]);
    atomicAdd(&colsum[threadIdx.x], lbin[threadIdx.x]);
  }
}

// ---------------- scan bases (128-aligned segments) + loss ----------------
__global__ void scan_loss_kernel(const int* __restrict__ counts, int* __restrict__ base,
                                 const float* __restrict__ colsum, float* __restrict__ loss_out)
{
  if (threadIdx.x == 0 && blockIdx.x == 0) {
    int acc = 0;
    for (int e = 0; e < NEXP; e++) { base[e] = acc; acc += (counts[e] + 127) & ~127; }
    base[NEXP] = acc;
    double s = 0.0;
    for (int e = 0; e < NEXP; e++) { double c = (double)colsum[e]; s += c * c; }
    loss_out[0] = (float)(1.6 * s / ((double)NTOK * (double)NTOK));
  }
}

// ---------------- scatter: wave-aggregated cursor atomics; records slot positions ----------------
__global__ __launch_bounds__(256) void scatter_kernel(
    const int2* __restrict__ eidx, const int* __restrict__ base, int* __restrict__ cursor,
    int* __restrict__ tok, int2* __restrict__ spos)
{
  int n = blockIdx.x * 256 + threadIdx.x;
  int lane = threadIdx.x & 63;
  int2 e = eidx[n];
  int myE[2] = {e.x, e.y};
  int myPos[2];
#pragma unroll
  for (int s = 0; s < 2; s++) {
    int eq = myE[s];
#pragma unroll
    for (int q = 0; q < NEXP; q++) {
      unsigned long long m = __ballot(eq == q);
      if (eq == q) {
        int cnt = __popcll(m);
        int pre = __popcll(m & ((1ull << lane) - 1ull));
        int b = 0;
        if (pre == 0) b = atomicAdd(&cursor[q], cnt);
        int leader = __ffsll((long long)m) - 1;
        b = __shfl(b, leader, 64);
        int pos = base[q] + b + pre;
        tok[pos] = n;
        myPos[s] = pos;
      }
    }
  }
  spos[n] = make_int2(myPos[0], myPos[1]);
}

// ---------------- grouped expert down-proj: bf16 MFMA, 128x128 tile, BK=64, split-K ----------------
// LDS layout: group g=row>>3 (1KB blocks), within: chunk (kc*8 + row&7)*16B  ->  conflict-floor
// ds_read_b128 (8 addrs per 4-bank group) while keeping each global_load_lds 1KB contiguous.
__global__ __launch_bounds__(256) void down_mfma_kernel(
    const unsigned short* __restrict__ xb, const unsigned short* __restrict__ dwb,
    const int* __restrict__ base, const int* __restrict__ tok,
    unsigned short* __restrict__ seg, int kcount)
{
  __shared__ unsigned short smem[17408];   // staging: A[0..8191] B[8192..16383]; epi: 128x136
  unsigned short* As = smem;
  unsigned short* Bs = smem + 8192;

  int slot0 = blockIdx.x * 128;
  if (slot0 >= base[NEXP]) return;          // uniform per block
  int e = 0;
#pragma unroll
  for (int q = 1; q < NEXP; q++) if (base[q] <= slot0) e = q;
  int out0 = blockIdx.y * 128;
  int kh   = blockIdx.z;
  int kbase = kh * kcount * 64;

  int tid = threadIdx.x;
  const int l = tid & 63, w = tid >> 6;
  const int wm = w & 1, wn = w >> 1;
  const int lm = l & 15, quad = l >> 4;

  const unsigned short* agp[4];
  const unsigned short* bgp[4];
#pragma unroll
  for (int i = 0; i < 4; i++) {
    int g = w * 4 + i;
    int r = g * 8 + (l & 7);
    int kc = l >> 3;
    int t = tok[slot0 + r];
    agp[i] = xb + (size_t)(t < 0 ? 0 : t) * HID + kbase + kc * 8;
    bgp[i] = dwb + ((size_t)e * DWN + out0 + r) * HID + kbase + kc * 8;
  }

  int am_off[4], bn_off[4];
#pragma unroll
  for (int mi = 0; mi < 4; mi++) {
    int m = wm * 64 + mi * 16 + lm;
    am_off[mi] = (m >> 3) * 512 + (m & 7) * 8 + quad * 64;
    int nn = wn * 64 + mi * 16 + lm;
    bn_off[mi] = (nn >> 3) * 512 + (nn & 7) * 8 + quad * 64;
  }

  f32x4 acc[4][4] = {};

  for (int it = 0; it < kcount; it++) {
    int k0 = it * 64;
    __syncthreads();
#pragma unroll
    for (int i = 0; i < 4; i++) {
      int g = w * 4 + i;
      ASYNC16(agp[i] + k0, &As[g * 512]);
      ASYNC16(bgp[i] + k0, &Bs[g * 512]);
    }
    __syncthreads();
#pragma unroll
    for (int kk = 0; kk < 2; kk++) {
      bf16x8 af[4], bfr[4];
#pragma unroll
      for (int mi = 0; mi < 4; mi++) af[mi]  = *(const bf16x8*)&As[am_off[mi] + kk * 256];
#pragma unroll
      for (int ni = 0; ni < 4; ni++) bfr[ni] = *(const bf16x8*)&Bs[bn_off[ni] + kk * 256];
#pragma unroll
      for (int mi = 0; mi < 4; mi++)
#pragma unroll
        for (int ni = 0; ni < 4; ni++)
          acc[mi][ni] = __builtin_amdgcn_mfma_f32_16x16x32_bf16(af[mi], bfr[ni], acc[mi][ni], 0, 0, 0);
    }
  }

  // epilogue: stage bf16 tile in LDS (stride 136 shorts = 272B, 16B-aligned, bank-spread),
  // then fully-coalesced 16B global stores. No atomics.
  __syncthreads();
#pragma unroll
  for (int mi = 0; mi < 4; mi++)
#pragma unroll
    for (int reg = 0; reg < 4; reg++) {
      int m = wm * 64 + mi * 16 + quad * 4 + reg;
#pragma unroll
      for (int ni = 0; ni < 4; ni++) {
        int c = wn * 64 + ni * 16 + lm;
        smem[m * 136 + c] = f2bf(acc[mi][ni][reg]);
      }
    }
  __syncthreads();
#pragma unroll
  for (int it2 = 0; it2 < 8; it2++) {
    int chunk = it2 * 256 + tid;
    int row = chunk >> 4, off = (chunk & 15) * 8;
    uint4 v = *(const uint4*)&smem[row * 136 + off];
    *(uint4*)&seg[(size_t)kh * SEGHALF_SHORTS + (size_t)(slot0 + row) * 512 + out0 + off] = v;
  }
}

// ---------------- combine (gather 2 slots x ksplit halves) + bias + gelu_new -> h bf16 ----------------
__global__ __launch_bounds__(256) void combine_gelu_kernel(
    const unsigned short* __restrict__ seg, const int2* __restrict__ spos,
    const float2* __restrict__ pv, const int2* __restrict__ eix,
    const float* __restrict__ db, unsigned short* __restrict__ h, int ksplit)
{
  int n = blockIdx.x * 4 + (threadIdx.x >> 6);
  int lane = threadIdx.x & 63;
  int c0 = lane * 8;
  int2 sp = spos[n];
  float2 p = pv[n];
  int2 e = eix[n];

  float d0[8] = {0,0,0,0,0,0,0,0}, d1[8] = {0,0,0,0,0,0,0,0};
  for (int hh = 0; hh < ksplit; hh++) {
    uint4 u0 = *(const uint4*)(seg + (size_t)hh * SEGHALF_SHORTS + (size_t)sp.x * 512 + c0);
    uint4 u1 = *(const uint4*)(seg + (size_t)hh * SEGHALF_SHORTS + (size_t)sp.y * 512 + c0);
    const unsigned short* s0 = (const unsigned short*)&u0;
    const unsigned short* s1 = (const unsigned short*)&u1;
#pragma unroll
    for (int j = 0; j < 8; j++) { d0[j] += bf2f(s0[j]); d1[j] += bf2f(s1[j]); }
  }
  float b0[8], b1[8];
  *(float4*)&b0[0] = *(const float4*)(db + e.x * DWN + c0);
  *(float4*)&b0[4] = *(const float4*)(db + e.x * DWN + c0 + 4);
  *(float4*)&b1[0] = *(const float4*)(db + e.y * DWN + c0);
  *(float4*)&b1[4] = *(const float4*)(db + e.y * DWN + c0 + 4);

  unsigned short o[8];
#pragma unroll
  for (int j = 0; j < 8; j++) {
    float xx = p.x * (d0[j] + b0[j]) + p.y * (d1[j] + b1[j]);
    float inner = 0.7978845608028654f * (xx + 0.044715f * xx * xx * xx);
    o[j] = f2bf(0.5f * xx * (1.0f + tanhf(inner)));
  }
  *(uint4*)(h + (size_t)n * DWN + c0) = *(const uint4*)o;
}

// ---------------- up-proj: bf16 MFMA, 128x128 tile, BK=64, K=512, conflict-floor LDS ----------------
__global__ __launch_bounds__(256) void up_mfma_kernel(
    const unsigned short* __restrict__ h, const unsigned short* __restrict__ uwb,
    const float* __restrict__ ub, float* __restrict__ out)
{
  __shared__ unsigned short smem[16384];
  unsigned short* As = smem;
  unsigned short* Bs = smem + 8192;

  int row0 = blockIdx.x * 128;
  int col0 = blockIdx.y * 128;
  int tid = threadIdx.x;
  const int l = tid & 63, w = tid >> 6;
  const int wm = w & 1, wn = w >> 1;
  const int lm = l & 15, quad = l >> 4;

  const unsigned short* agp[4];
  const unsigned short* bgp[4];
#pragma unroll
  for (int i = 0; i < 4; i++) {
    int g = w * 4 + i;
    int r = g * 8 + (l & 7);
    int kc = l >> 3;
    agp[i] = h   + (size_t)(row0 + r) * DWN + kc * 8;
    bgp[i] = uwb + (size_t)(col0 + r) * DWN + kc * 8;
  }

  int am_off[4], bn_off[4];
#pragma unroll
  for (int mi = 0; mi < 4; mi++) {
    int m = wm * 64 + mi * 16 + lm;
    am_off[mi] = (m >> 3) * 512 + (m & 7) * 8 + quad * 64;
    int nn = wn * 64 + mi * 16 + lm;
    bn_off[mi] = (nn >> 3) * 512 + (nn & 7) * 8 + quad * 64;
  }

  f32x4 acc[4][4] = {};

  for (int k0 = 0; k0 < DWN; k0 += 64) {
    __syncthreads();
#pragma unroll
    for (int i = 0; i < 4; i++) {
      int g = w * 4 + i;
      ASYNC16(agp[i] + k0, &As[g * 512]);
      ASYNC16(bgp[i] + k0, &Bs[g * 512]);
    }
    __syncthreads();
#pragma unroll
    for (int kk = 0; kk < 2; kk++) {
      bf16x8 af[4], bfr[4];
#pragma unroll
      for (int mi = 0; mi < 4; mi++) af[mi]  = *(const bf16x8*)&As[am_off[mi] + kk * 256];
#pragma unroll
      for (int ni = 0; ni < 4; ni++) bfr[ni] = *(const bf16x8*)&Bs[bn_off[ni] + kk * 256];
#pragma unroll
      for (int mi = 0; mi < 4; mi++)
#pragma unroll
        for (int ni = 0; ni < 4; ni++)
          acc[mi][ni] = __builtin_amdgcn_mfma_f32_16x16x32_bf16(af[mi], bfr[ni], acc[mi][ni], 0, 0, 0);
    }
  }

  float ubv[4];
#pragma unroll
  for (int ni = 0; ni < 4; ni++)
    ubv[ni] = ub[col0 + wn * 64 + ni * 16 + lm];
#pragma unroll
  for (int mi = 0; mi < 4; mi++) {
#pragma unroll
    for (int reg = 0; reg < 4; reg++) {
      int m = row0 + wm * 64 + mi * 16 + quad * 4 + reg;
      float* orow = out + (size_t)m * HID;
#pragma unroll
      for (int ni = 0; ni < 4; ni++) {
        int gc = col0 + wn * 64 + ni * 16 + lm;
        orow[gc] = acc[mi][ni][reg] + ubv[ni];
      }
    }
  }
}

extern "C" void kernel_launch(void* const* d_in, const int* in_sizes, int n_in,
                              void* d_out, int out_size, void* d_ws, size_t ws_size,
                              hipStream_t stream)
{
  const float* x  = (const float*)d_in[0];
  const float* gw = (const float*)d_in[1];
  const float* dw = (const float*)d_in[2];
  const float* db = (const float*)d_in[3];
  const float* uw = (const float*)d_in[4];
  const float* ub = (const float*)d_in[5];
  float* out = (float*)d_out;

  char* ws = (char*)d_ws;
  unsigned short* xb   = (unsigned short*)(ws + OFF_XB);
  unsigned short* dwb  = (unsigned short*)(ws + OFF_DWB);
  unsigned short* uwb  = (unsigned short*)(ws + OFF_UWB);
  unsigned short* h    = (unsigned short*)(ws + OFF_H);
  unsigned short* seg  = (unsigned short*)(ws + OFF_SEG);
  int*    tok    = (int*)(ws + OFF_TOK);
  int2*   spos   = (int2*)(ws + OFF_SPOS);
  int2*   eidx   = (int2*)(ws + OFF_EIDX);
  float2* pvals  = (float2*)(ws + OFF_PVAL);
  int*    counts = (int*)(ws + OFF_COUNTS);
  int*    base   = (int*)(ws + OFF_BASE);
  int*    cursor = (int*)(ws + OFF_CURSOR);
  float*  colsum = (float*)(ws + OFF_COLSUM);

  // split-K only if the workspace is big enough (ws_size constant per session -> same work each call)
  const int ksplit = (ws_size >= (size_t)WS_NEED2) ? 2 : 1;
  const int kcount = (HID / 64) / ksplit;

  hipMemsetAsync(tok, 0xFF, PADSLOT * sizeof(int), stream);     // token = -1 padding
  hipMemsetAsync(counts, 0, 320, stream);                        // counts/base/cursor/colsum

  cast8_kernel<<<(NTOK * HID) / 8 / 256, 256, 0, stream>>>(x, xb);
  cast8_kernel<<<(NEXP * DWN * HID) / 8 / 256, 256, 0, stream>>>(dw, dwb);
  cast8_kernel<<<(HID * DWN) / 8 / 256, 256, 0, stream>>>(uw, uwb);

  gate_kernel<<<NTOK / 4, 256, 0, stream>>>(x, gw, eidx, pvals);
  hist_kernel<<<NTOK / 256, 256, 0, stream>>>(eidx, pvals, counts, colsum);
  scan_loss_kernel<<<1, 64, 0, stream>>>(counts, base, colsum, out + (size_t)NTOK * HID);
  scatter_kernel<<<NTOK / 256, 256, 0, stream>>>(eidx, base, cursor, tok, spos);

  dim3 gdown(PADSLOT / 128, DWN / 128, ksplit);   // 144 x 4 x ksplit
  down_mfma_kernel<<<gdown, 256, 0, stream>>>(xb, dwb, base, tok, seg, kcount);

  combine_gelu_kernel<<<NTOK / 4, 256, 0, stream>>>(seg, spos, pvals, eidx, db, h, ksplit);

  dim3 gup(NTOK / 128, HID / 128);                // 64 x 16
  up_mfma_kernel<<<gup, 256, 0, stream>>>(h, uwb, ub, out);
}